// Round 22
// baseline (376.200 us; speedup 1.0000x reference)
//
#include <hip/hip_runtime.h>
#include <math.h>

// ---------------- geometry ----------------
// x: [img][3][160][60], img 0..127 (0..63 = x1, 64..127 = x2)
// conv1 5x5 VALID -> [20][156][56], relu, pool2 -> [20][78][28]
// conv2 5x5 VALID -> [25][74][24], relu, pool2 -> f [25][37][12]
// stats (in k_ncc): mu, 1/(std+0.01) per (img,c,i,j) over zero-padded 5x5 patch
// ncc = (dot - 25 muX muY) * invX * invY / 25 ; relu; 1x1 conv w_red1 -> [64][25][37][12]
// red2 3x3 VALID -> [35][10], pool2 -> [17][5]; flatten 2125; lin1 2125->500; lin2 500->2

// ws offsets in floats
static const long OFF_C1   = 0;          // [128][20][78][28] = 5,591,040
static const long OFF_F    = 5591040;    // [128][25][444]    = 1,420,800
// overlays of the dead-c1 region (valid after conv2 completes):
static const long OFF_RED1 = 3552000;    // [64][25][444] = 710,400
static const long OFF_R2P  = 4262400;    // [64][2125]    = 136,000 (ends 4,398,400)
static const long OFF_WR1T = 4500000;    // [1500][28] = 42,000 (written after conv2)
static const long OFF_LINP = 0;          // lin1 partials [17][64][512] = 557,056 (after red2)

// ---------------- w_red1 transpose (row-padded to 28): wr1t[t][o] ----------------
__global__ void k_wrt(const float* __restrict__ wr1, float* __restrict__ wr1t) {
  int idx = blockIdx.x * 256 + threadIdx.x;
  if (idx < 37500) {
    int o = idx / 1500, t = idx % 1500;
    wr1t[t * 28 + o] = wr1[idx];
  }
}

// ---------------- conv1 + relu + pool (256 thr, all-ic LDS, NOC=5, float2 wins) ---
__global__ __launch_bounds__(256) void k_conv1(
    const float* __restrict__ x1, const float* __restrict__ x2,
    const float* __restrict__ w, const float* __restrict__ bias,
    float* __restrict__ out) {
  int img = blockIdx.x;
  int g   = blockIdx.y;          // 0..5, 13 pooled rows each (78 = 6*13)
  int oc0 = blockIdx.z * 5;      // 0,5,10,15
  int p0  = g * 13;
  int R0  = 2 * p0;              // first input row needed; 30 rows, 60 cols
  int tid = threadIdx.x;
  const float* x = (img < 64) ? (x1 + (long)img * 28800)
                              : (x2 + (long)(img - 64) * 28800);
  __shared__ __align__(16) float tile[3][30][60];   // 21.6 KB -> 7 blocks/CU

#pragma unroll
  for (int ic = 0; ic < 3; ++ic) {
    const float* src = x + ic * 9600 + R0 * 60;
    float* dst = &tile[ic][0][0];
    for (int off = tid; off < 1800; off += 256) dst[off] = src[off];
  }
  __syncthreads();

  for (int item = tid; item < 364; item += 256) {
    int r = item / 28, j = item % 28;
    int lr = 2 * r, lc = 2 * j;
    float acc[5][4];
#pragma unroll
    for (int o = 0; o < 5; ++o) {
      acc[o][0] = 0.f; acc[o][1] = 0.f; acc[o][2] = 0.f; acc[o][3] = 0.f;
    }
#pragma unroll
    for (int ic = 0; ic < 3; ++ic) {
      float win[6][6];
#pragma unroll
      for (int u = 0; u < 6; ++u) {
        const float* rp = &tile[ic][lr + u][lc];
        float2 a = *reinterpret_cast<const float2*>(rp);
        float2 b = *reinterpret_cast<const float2*>(rp + 2);
        float2 c = *reinterpret_cast<const float2*>(rp + 4);
        win[u][0] = a.x; win[u][1] = a.y; win[u][2] = b.x;
        win[u][3] = b.y; win[u][4] = c.x; win[u][5] = c.y;
      }
#pragma unroll
      for (int o = 0; o < 5; ++o) {
        const float* wq = w + ((oc0 + o) * 3 + ic) * 25;
#pragma unroll
        for (int u = 0; u < 5; ++u)
#pragma unroll
          for (int v = 0; v < 5; ++v) {
            float wv = wq[u * 5 + v];
            acc[o][0] = fmaf(wv, win[u][v], acc[o][0]);
            acc[o][1] = fmaf(wv, win[u][v + 1], acc[o][1]);
            acc[o][2] = fmaf(wv, win[u + 1][v], acc[o][2]);
            acc[o][3] = fmaf(wv, win[u + 1][v + 1], acc[o][3]);
          }
      }
    }
#pragma unroll
    for (int o = 0; o < 5; ++o) {
      float mx = fmaxf(fmaxf(acc[o][0], acc[o][1]), fmaxf(acc[o][2], acc[o][3]));
      out[((long)img * 20 + oc0 + o) * 2184 + (p0 + r) * 28 + j] =
          fmaxf(mx + bias[oc0 + o], 0.f);
    }
  }
}

// ---------------- conv2 + relu + pool (team-split: 2 oc-groups share staged tile) -
// 256 threads = 2 teams of 128 (120 active each). Team t computes oc-group
// z*10 + t*5; both teams share one swizzled LDS tile (staged by all 256).
__global__ __launch_bounds__(256) void k_conv2(
    const float* __restrict__ in, const float* __restrict__ w,
    const float* __restrict__ bias, float* __restrict__ out) {
  int img = blockIdx.x;
  int g   = blockIdx.y;          // 0..3 -> pooled rows p0..p0+9 (last: 7)
  int z   = blockIdx.z;          // 0..2 -> oc0 = z*10 (+5 for team 1)
  int p0  = g * 10;
  int ROWS = min(10, 37 - p0);
  int R0  = 2 * p0;
  int NR  = 2 * ROWS + 4;        // 24 (or 18 for last group)
  int tid = threadIdx.x;
  int team = tid >> 7;           // 0,1
  int rem  = tid & 127;
  int r = rem / 12, j = rem % 12;
  int oc0 = z * 10 + team * 5;   // 0,5 / 10,15 / 20,25(idle)
  bool active = (rem < 120) && (r < ROWS) && (oc0 < 25);
  const float* xin = in + (long)img * 43680;
  __shared__ float tile[2][24][43];   // 8.1 KB

  {
    const float* src = xin + R0 * 28;
    for (int idx = tid; idx < NR * 28; idx += 256) {
      int row = idx / 28, col = idx - row * 28;
      tile[0][row][col + (col >> 1)] = src[idx];
    }
  }

  float acc[5][4];
#pragma unroll
  for (int o = 0; o < 5; ++o) {
    acc[o][0] = 0.f; acc[o][1] = 0.f; acc[o][2] = 0.f; acc[o][3] = 0.f;
  }
  int lr = 2 * r;
  int cb = 3 * j;                // swizzled base for col 2j

  for (int ic = 0; ic < 20; ++ic) {
    __syncthreads();
    if (ic < 19) {
      const float* src = xin + (ic + 1) * 2184 + R0 * 28;
      int nxt = (ic + 1) & 1;
      for (int idx = tid; idx < NR * 28; idx += 256) {
        int row = idx / 28, col = idx - row * 28;
        tile[nxt][row][col + (col >> 1)] = src[idx];
      }
    }
    if (active) {
      int cur = ic & 1;
      float win[6][6];
#pragma unroll
      for (int u = 0; u < 6; ++u) {
        const float* rp = &tile[cur][lr + u][cb];
        win[u][0] = rp[0]; win[u][1] = rp[1]; win[u][2] = rp[3];
        win[u][3] = rp[4]; win[u][4] = rp[6]; win[u][5] = rp[7];
      }
#pragma unroll
      for (int o = 0; o < 5; ++o) {
        const float* wq = w + ((oc0 + o) * 20 + ic) * 25;
#pragma unroll
        for (int u = 0; u < 5; ++u)
#pragma unroll
          for (int v = 0; v < 5; ++v) {
            float wv = wq[u * 5 + v];
            acc[o][0] = fmaf(wv, win[u][v], acc[o][0]);
            acc[o][1] = fmaf(wv, win[u][v + 1], acc[o][1]);
            acc[o][2] = fmaf(wv, win[u + 1][v], acc[o][2]);
            acc[o][3] = fmaf(wv, win[u + 1][v + 1], acc[o][3]);
          }
      }
    }
  }

  if (active) {
#pragma unroll
    for (int o = 0; o < 5; ++o) {
      float mx = fmaxf(fmaxf(acc[o][0], acc[o][1]), fmaxf(acc[o][2], acc[o][3]));
      out[((long)img * 25 + oc0 + o) * 444 + (p0 + r) * 12 + j] =
          fmaxf(mx + bias[oc0 + o], 0.f);
    }
  }
}

// ---------------- fused stats + NCC + relu + red1 (one channel per block) ---------
__global__ __launch_bounds__(128) void k_ncc(
    const float* __restrict__ f, const float* __restrict__ wr1t,
    float* __restrict__ red1) {
  int b  = blockIdx.x;          // 0..63
  int g  = blockIdx.y;          // 0..3 -> rows i0..i0+ROWS-1
  int c  = blockIdx.z;          // 0..24 channel
  int i0 = g * 10;
  int ROWS = min(10, 37 - i0);
  int tid = threadIdx.x;
  int j = tid % 12, r = tid / 12;
  bool active = (r < ROWS);

  __shared__ float Xt[14][17];
  __shared__ __align__(16) float Yt[18][20];
  __shared__ float mX[10][12], iX[10][12];
  __shared__ float mY[14][12], iY[14][12];   // mY = muY*ivY, iY = ivY

  const float* Xf = f + (long)b * 25 * 444 + c * 444;
  const float* Yf = f + (long)(64 + b) * 25 * 444 + c * 444;

  for (int idx = tid; idx < 14 * 16; idx += 128) {
    int rr = idx >> 4, cl = idx & 15;
    int gi = i0 - 2 + rr, gj = cl - 2;
    Xt[rr][cl] = (gi >= 0 && gi < 37 && gj >= 0 && gj < 12)
                     ? Xf[gi * 12 + gj] : 0.f;
  }
  for (int idx = tid; idx < 18 * 16; idx += 128) {
    int rr = idx >> 4, cl = idx & 15;
    int gi = i0 - 4 + rr, gj = cl - 2;
    Yt[rr][cl] = (gi >= 0 && gi < 37 && gj >= 0 && gj < 12)
                     ? Yf[gi * 12 + gj] : 0.f;
  }
  for (int idx = tid; idx < 18 * 4; idx += 128) {
    int rr = idx >> 2;
    Yt[rr][16 + (idx & 3)] = 0.f;   // pad cols 16..19
  }
  __syncthreads();

  // ---- in-block patch stats from staged tiles ----
  for (int idx = tid; idx < 120; idx += 128) {
    int rr = idx / 12, gj = idx % 12;
    bool ok = (i0 + rr) < 37;
    float s = 0.f, sq = 0.f;
#pragma unroll
    for (int u = 0; u < 5; ++u)
#pragma unroll
      for (int v = 0; v < 5; ++v) {
        float xv = Xt[rr + u][gj + v];
        s += xv;
        sq = fmaf(xv, xv, sq);
      }
    float m = s * 0.04f;
    float var = sq * 0.04f - m * m;
    float sd = sqrtf(fmaxf(var, 0.f));
    float ivv = 1.f / (sd + 0.01f);
    mX[rr][gj] = ok ? m : 0.f;
    iX[rr][gj] = ok ? ivv : 0.f;
  }
  for (int idx = tid; idx < 168; idx += 128) {
    int rr = idx / 12, gj = idx % 12;
    int gi = i0 - 2 + rr;
    bool ok = (gi >= 0 && gi < 37);
    float s = 0.f, sq = 0.f;
#pragma unroll
    for (int u = 0; u < 5; ++u)
#pragma unroll
      for (int v = 0; v < 5; ++v) {
        float yv = Yt[rr + u][gj + v];
        s += yv;
        sq = fmaf(yv, yv, sq);
      }
    float m = s * 0.04f;
    float var = sq * 0.04f - m * m;
    float sd = sqrtf(fmaxf(var, 0.f));
    float ivv = 1.f / (sd + 0.01f);
    mY[rr][gj] = ok ? m * ivv : 0.f;
    iY[rr][gj] = ok ? ivv : 0.f;
  }
  __syncthreads();

  float acc[25];
#pragma unroll
  for (int o = 0; o < 25; ++o) acc[o] = 0.f;

  if (active) {
    float xp[5][5];
#pragma unroll
    for (int u = 0; u < 5; ++u)
#pragma unroll
      for (int v = 0; v < 5; ++v) xp[u][v] = Xt[r + u][j + v];
    float muXv = mX[r][j], ivXv = iX[r][j];
    float sX = ivXv * 0.04f;
    float tX = muXv * ivXv;
    const float* wb = wr1t + c * 1680;     // 60 rows * 28 padded
#pragma unroll 1
    for (int d = 0; d < 5; ++d) {
      float rd[12];
#pragma unroll
      for (int k = 0; k < 12; ++k) rd[k] = 0.f;
#pragma unroll
      for (int u = 0; u < 5; ++u) {
        float yrow[16];
        const float* yb = &Yt[r + d + u][0];
        *reinterpret_cast<float4*>(&yrow[0])  = *reinterpret_cast<const float4*>(yb);
        *reinterpret_cast<float4*>(&yrow[4])  = *reinterpret_cast<const float4*>(yb + 4);
        *reinterpret_cast<float4*>(&yrow[8])  = *reinterpret_cast<const float4*>(yb + 8);
        *reinterpret_cast<float4*>(&yrow[12]) = *reinterpret_cast<const float4*>(yb + 12);
#pragma unroll
        for (int k = 0; k < 12; ++k)
#pragma unroll
          for (int v = 0; v < 5; ++v)
            rd[k] = fmaf(xp[u][v], yrow[k + v], rd[k]);
      }
#pragma unroll
      for (int k = 0; k < 12; ++k) {
        float ivYv = iY[r + d][k];
        float miYv = mY[r + d][k];
        float rv = fmaxf(fmaf(-tX, miYv, rd[k] * sX * ivYv), 0.f);
        const float* wrow = wb + (d * 12 + k) * 28;
        float wv[25];
        *reinterpret_cast<float4*>(&wv[0])  = *reinterpret_cast<const float4*>(wrow);
        *reinterpret_cast<float4*>(&wv[4])  = *reinterpret_cast<const float4*>(wrow + 4);
        *reinterpret_cast<float4*>(&wv[8])  = *reinterpret_cast<const float4*>(wrow + 8);
        *reinterpret_cast<float4*>(&wv[12]) = *reinterpret_cast<const float4*>(wrow + 12);
        *reinterpret_cast<float4*>(&wv[16]) = *reinterpret_cast<const float4*>(wrow + 16);
        *reinterpret_cast<float4*>(&wv[20]) = *reinterpret_cast<const float4*>(wrow + 20);
        wv[24] = wrow[24];
#pragma unroll
        for (int o = 0; o < 25; ++o) acc[o] = fmaf(wv[o], rv, acc[o]);
      }
    }
  }

  if (active) {
    int i = i0 + r;
    float* p = red1 + (long)b * 25 * 444 + i * 12 + j;
#pragma unroll
    for (int o = 0; o < 25; ++o) atomicAdd(p + o * 444, acc[o]);
  }
}

// ---------------- red2 3x3 conv + pool (oc-group split; bias+relu on load) --------
__global__ __launch_bounds__(256) void k_red2(
    const float* __restrict__ red1, const float* __restrict__ br1,
    const float* __restrict__ w, const float* __restrict__ bias,
    float* __restrict__ r2p) {
  int b = blockIdx.x;
  int oc0 = blockIdx.y * 5;
  __shared__ float inb[25 * 444];
  __shared__ float wl[5 * 25 * 9];
  for (int idx = threadIdx.x; idx < 25 * 444; idx += 256)
    inb[idx] = fmaxf(red1[(long)b * 25 * 444 + idx] + br1[idx / 444], 0.f);
  for (int idx = threadIdx.x; idx < 5 * 25 * 9; idx += 256)
    wl[idx] = w[oc0 * 25 * 9 + idx];
  __syncthreads();
  for (int item = threadIdx.x; item < 5 * 85; item += 256) {
    int ol = item / 85, rem = item % 85;
    int pi = rem / 5, pj = rem % 5;
    int ci0 = 2 * pi, cj0 = 2 * pj;
    float a00 = 0, a01 = 0, a10 = 0, a11 = 0;
    for (int ic = 0; ic < 25; ++ic) {
      const float* xp = inb + ic * 444 + ci0 * 12 + cj0;
      float win[4][4];
#pragma unroll
      for (int u = 0; u < 4; ++u)
#pragma unroll
        for (int v = 0; v < 4; ++v) win[u][v] = xp[u * 12 + v];
      const float* wq = wl + (ol * 25 + ic) * 9;
#pragma unroll
      for (int u = 0; u < 3; ++u)
#pragma unroll
        for (int v = 0; v < 3; ++v) {
          float wv = wq[u * 3 + v];
          a00 += wv * win[u][v];
          a01 += wv * win[u][v + 1];
          a10 += wv * win[u + 1][v];
          a11 += wv * win[u + 1][v + 1];
        }
    }
    float mx = fmaxf(fmaxf(a00, a01), fmaxf(a10, a11));
    r2p[(long)b * 2125 + (oc0 + ol) * 85 + rem] = mx + bias[oc0 + ol];
  }
}

// ---------------- lin1 GEMM partials (reads wl1 directly, no pre-transpose) -------
__global__ __launch_bounds__(256) void k_lin1p(
    const float* __restrict__ r2p, const float* __restrict__ wl1,
    float* __restrict__ part) {
  int nb = blockIdx.x;           // o-tile: o0 = nb*64
  int kc = blockIdx.y;           // t-chunk: t0 = kc*125
  int o0 = nb * 64, t0 = kc * 125;
  int tid = threadIdx.x;
  __shared__ float Xs[64][126];
  __shared__ __align__(16) float Ws[125][68];
  for (int idx = tid; idx < 64 * 125; idx += 256) {
    int b = idx / 125, tt = idx % 125;
    Xs[b][tt] = r2p[(long)b * 2125 + t0 + tt];
  }
  for (int idx = tid; idx < 64 * 125; idx += 256) {
    int oo = idx / 125, tt = idx % 125;
    int o = o0 + oo;
    Ws[tt][oo] = (o < 500) ? wl1[(long)o * 2125 + t0 + tt] : 0.f;
  }
  __syncthreads();
  int b0 = (tid >> 4) << 2;
  int ol = (tid & 15) << 2;
  float acc[4][4];
#pragma unroll
  for (int i = 0; i < 4; ++i)
#pragma unroll
    for (int q = 0; q < 4; ++q) acc[i][q] = 0.f;
  for (int tt = 0; tt < 125; ++tt) {
    float xv[4];
#pragma unroll
    for (int i = 0; i < 4; ++i) xv[i] = Xs[b0 + i][tt];
    float4 wv = *reinterpret_cast<const float4*>(&Ws[tt][ol]);
#pragma unroll
    for (int i = 0; i < 4; ++i) {
      acc[i][0] += xv[i] * wv.x;
      acc[i][1] += xv[i] * wv.y;
      acc[i][2] += xv[i] * wv.z;
      acc[i][3] += xv[i] * wv.w;
    }
  }
#pragma unroll
  for (int i = 0; i < 4; ++i)
#pragma unroll
    for (int q = 0; q < 4; ++q)
      part[((long)kc * 64 + (b0 + i)) * 512 + o0 + ol + q] = acc[i][q];
}

// ---------------- lin1 reduce + bias, then lin2 fused ----------------
__global__ __launch_bounds__(512) void k_lin2(
    const float* __restrict__ part, const float* __restrict__ bl1,
    const float* __restrict__ wl2, const float* __restrict__ bl2,
    float* __restrict__ out) {
  int b = blockIdx.x;
  int o = threadIdx.x;
  float s = 0.f;
  if (o < 500) {
#pragma unroll
    for (int kc = 0; kc < 17; ++kc) s += part[((long)kc * 64 + b) * 512 + o];
    s += bl1[o];
  }
  __shared__ float red0[512], red1s[512];
  red0[o]  = (o < 500) ? s * wl2[o] : 0.f;
  red1s[o] = (o < 500) ? s * wl2[500 + o] : 0.f;
  __syncthreads();
  for (int st = 256; st >= 1; st >>= 1) {
    if (o < st) { red0[o] += red0[o + st]; red1s[o] += red1s[o + st]; }
    __syncthreads();
  }
  if (o == 0) {
    out[b * 2 + 0] = red0[0] + bl2[0];
    out[b * 2 + 1] = red1s[0] + bl2[1];
  }
}

// ---------------- launch ----------------
extern "C" void kernel_launch(void* const* d_in, const int* in_sizes, int n_in,
                              void* d_out, int out_size, void* d_ws, size_t ws_size,
                              hipStream_t stream) {
  const float* x1   = (const float*)d_in[0];
  const float* x2   = (const float*)d_in[1];
  const float* w1   = (const float*)d_in[2];
  const float* b1   = (const float*)d_in[3];
  const float* w2   = (const float*)d_in[4];
  const float* b2   = (const float*)d_in[5];
  const float* wr1  = (const float*)d_in[6];
  const float* br1  = (const float*)d_in[7];
  const float* wr2  = (const float*)d_in[8];
  const float* br2  = (const float*)d_in[9];
  const float* wl1  = (const float*)d_in[10];
  const float* bl1  = (const float*)d_in[11];
  const float* wl2  = (const float*)d_in[12];
  const float* bl2  = (const float*)d_in[13];
  float* out = (float*)d_out;
  float* ws  = (float*)d_ws;

  float* c1    = ws + OFF_C1;
  float* f     = ws + OFF_F;
  float* red1  = ws + OFF_RED1;
  float* r2p   = ws + OFF_R2P;
  float* wr1t  = ws + OFF_WR1T;
  float* linp  = ws + OFF_LINP;

  hipLaunchKernelGGL(k_conv1, dim3(128, 6, 4), dim3(256), 0, stream, x1, x2, w1, b1, c1);
  hipLaunchKernelGGL(k_conv2, dim3(128, 4, 3), dim3(256), 0, stream, c1, w2, b2, f);

  // wr1t lives in the (now dead) c1 region -> must launch after conv2
  hipLaunchKernelGGL(k_wrt, dim3(147), dim3(256), 0, stream, wr1, wr1t);

  // zero red1 accumulator (graph-capturable stream op), then fused stats+NCC+red1
  hipMemsetAsync(red1, 0, 710400 * sizeof(float), stream);
  hipLaunchKernelGGL(k_ncc, dim3(64, 4, 25), dim3(128), 0, stream, f, wr1t, red1);

  hipLaunchKernelGGL(k_red2, dim3(64, 5), dim3(256), 0, stream, red1, br1, wr2, br2, r2p);

  hipLaunchKernelGGL(k_lin1p, dim3(8, 17), dim3(256), 0, stream, r2p, wl1, linp);
  hipLaunchKernelGGL(k_lin2, dim3(64), dim3(512), 0, stream, linp, bl1, wl2, bl2, out);
}

// Round 23
// 313.791 us; speedup vs baseline: 1.1989x; 1.1989x over previous
//
#include <hip/hip_runtime.h>
#include <math.h>

// ---------------- geometry ----------------
// x: [img][3][160][60], img 0..127 (0..63 = x1, 64..127 = x2)
// conv1 5x5 VALID -> [20][156][56], relu, pool2 -> [20][78][28]
// conv2 5x5 VALID -> [25][74][24], relu, pool2 -> f [25][37][12]
// stats (in k_ncc): mu, 1/(std+0.01) per (img,c,i,j) over zero-padded 5x5 patch
// ncc = (dot - 25 muX muY) * invX * invY / 25 ; relu; 1x1 conv w_red1 -> [64][25][37][12]
// red2 3x3 VALID -> [35][10], pool2 -> [17][5]; flatten 2125; lin1 2125->500; lin2 500->2

// ws offsets in floats
static const long OFF_C1   = 0;          // [128][20][78][28] = 5,591,040
static const long OFF_F    = 5591040;    // [128][25][444]    = 1,420,800
// overlays of the dead-c1 region (valid after conv2 completes):
static const long OFF_RED1 = 3552000;    // [64][25][444] = 710,400
static const long OFF_R2P  = 4262400;    // [64][2125]    = 136,000 (ends 4,398,400)
static const long OFF_WR1T = 4500000;    // [1500][28] = 42,000 (written after conv2)
static const long OFF_LINP = 0;          // lin1 partials [17][64][512] = 557,056 (after red2)

// ---------------- w_red1 transpose (row-padded to 28): wr1t[t][o] ----------------
__global__ void k_wrt(const float* __restrict__ wr1, float* __restrict__ wr1t) {
  int idx = blockIdx.x * 256 + threadIdx.x;
  if (idx < 37500) {
    int o = idx / 1500, t = idx % 1500;
    wr1t[t * 28 + o] = wr1[idx];
  }
}

// ---------------- conv1 + relu + pool (256 thr, all-ic LDS, NOC=5, float2 wins) ---
__global__ __launch_bounds__(256) void k_conv1(
    const float* __restrict__ x1, const float* __restrict__ x2,
    const float* __restrict__ w, const float* __restrict__ bias,
    float* __restrict__ out) {
  int img = blockIdx.x;
  int g   = blockIdx.y;          // 0..5, 13 pooled rows each (78 = 6*13)
  int oc0 = blockIdx.z * 5;      // 0,5,10,15
  int p0  = g * 13;
  int R0  = 2 * p0;              // first input row needed; 30 rows, 60 cols
  int tid = threadIdx.x;
  const float* x = (img < 64) ? (x1 + (long)img * 28800)
                              : (x2 + (long)(img - 64) * 28800);
  __shared__ __align__(16) float tile[3][30][60];   // 21.6 KB -> 7 blocks/CU

#pragma unroll
  for (int ic = 0; ic < 3; ++ic) {
    const float* src = x + ic * 9600 + R0 * 60;
    float* dst = &tile[ic][0][0];
    for (int off = tid; off < 1800; off += 256) dst[off] = src[off];
  }
  __syncthreads();

  for (int item = tid; item < 364; item += 256) {
    int r = item / 28, j = item % 28;
    int lr = 2 * r, lc = 2 * j;
    float acc[5][4];
#pragma unroll
    for (int o = 0; o < 5; ++o) {
      acc[o][0] = 0.f; acc[o][1] = 0.f; acc[o][2] = 0.f; acc[o][3] = 0.f;
    }
#pragma unroll
    for (int ic = 0; ic < 3; ++ic) {
      float win[6][6];
#pragma unroll
      for (int u = 0; u < 6; ++u) {
        const float* rp = &tile[ic][lr + u][lc];
        float2 a = *reinterpret_cast<const float2*>(rp);
        float2 b = *reinterpret_cast<const float2*>(rp + 2);
        float2 c = *reinterpret_cast<const float2*>(rp + 4);
        win[u][0] = a.x; win[u][1] = a.y; win[u][2] = b.x;
        win[u][3] = b.y; win[u][4] = c.x; win[u][5] = c.y;
      }
#pragma unroll
      for (int o = 0; o < 5; ++o) {
        const float* wq = w + ((oc0 + o) * 3 + ic) * 25;
#pragma unroll
        for (int u = 0; u < 5; ++u)
#pragma unroll
          for (int v = 0; v < 5; ++v) {
            float wv = wq[u * 5 + v];
            acc[o][0] = fmaf(wv, win[u][v], acc[o][0]);
            acc[o][1] = fmaf(wv, win[u][v + 1], acc[o][1]);
            acc[o][2] = fmaf(wv, win[u + 1][v], acc[o][2]);
            acc[o][3] = fmaf(wv, win[u + 1][v + 1], acc[o][3]);
          }
      }
    }
#pragma unroll
    for (int o = 0; o < 5; ++o) {
      float mx = fmaxf(fmaxf(acc[o][0], acc[o][1]), fmaxf(acc[o][2], acc[o][3]));
      out[((long)img * 20 + oc0 + o) * 2184 + (p0 + r) * 28 + j] =
          fmaxf(mx + bias[oc0 + o], 0.f);
    }
  }
}

// ---------------- conv2 + relu + pool (LDS dbuf, 1.5x column swizzle) -------------
__global__ __launch_bounds__(128) void k_conv2(
    const float* __restrict__ in, const float* __restrict__ w,
    const float* __restrict__ bias, float* __restrict__ out) {
  int img = blockIdx.x;
  int g   = blockIdx.y;          // 0..3 -> pooled rows p0..p0+9 (last: 7)
  int oc0 = blockIdx.z * 5;      // 0,5,10,15,20
  int p0  = g * 10;
  int ROWS = min(10, 37 - p0);
  int R0  = 2 * p0;
  int NR  = 2 * ROWS + 4;        // 24 (or 18 for last group)
  int tid = threadIdx.x;
  int r = tid / 12, j = tid % 12;
  bool active = (tid < 120) && (r < ROWS);
  const float* xin = in + (long)img * 43680;
  __shared__ float tile[2][24][43];   // 8.1 KB

  {
    const float* src = xin + R0 * 28;
    for (int idx = tid; idx < NR * 28; idx += 128) {
      int row = idx / 28, col = idx - row * 28;
      tile[0][row][col + (col >> 1)] = src[idx];
    }
  }

  float acc[5][4];
#pragma unroll
  for (int o = 0; o < 5; ++o) {
    acc[o][0] = 0.f; acc[o][1] = 0.f; acc[o][2] = 0.f; acc[o][3] = 0.f;
  }
  int lr = 2 * r;
  int cb = 3 * j;                // swizzled base for col 2j

  for (int ic = 0; ic < 20; ++ic) {
    __syncthreads();
    if (ic < 19) {
      const float* src = xin + (ic + 1) * 2184 + R0 * 28;
      int nxt = (ic + 1) & 1;
      for (int idx = tid; idx < NR * 28; idx += 128) {
        int row = idx / 28, col = idx - row * 28;
        tile[nxt][row][col + (col >> 1)] = src[idx];
      }
    }
    if (active) {
      int cur = ic & 1;
      float win[6][6];
#pragma unroll
      for (int u = 0; u < 6; ++u) {
        const float* rp = &tile[cur][lr + u][cb];
        win[u][0] = rp[0]; win[u][1] = rp[1]; win[u][2] = rp[3];
        win[u][3] = rp[4]; win[u][4] = rp[6]; win[u][5] = rp[7];
      }
#pragma unroll
      for (int o = 0; o < 5; ++o) {
        const float* wq = w + ((oc0 + o) * 20 + ic) * 25;
#pragma unroll
        for (int u = 0; u < 5; ++u)
#pragma unroll
          for (int v = 0; v < 5; ++v) {
            float wv = wq[u * 5 + v];
            acc[o][0] = fmaf(wv, win[u][v], acc[o][0]);
            acc[o][1] = fmaf(wv, win[u][v + 1], acc[o][1]);
            acc[o][2] = fmaf(wv, win[u + 1][v], acc[o][2]);
            acc[o][3] = fmaf(wv, win[u + 1][v + 1], acc[o][3]);
          }
      }
    }
  }

  if (active) {
#pragma unroll
    for (int o = 0; o < 5; ++o) {
      float mx = fmaxf(fmaxf(acc[o][0], acc[o][1]), fmaxf(acc[o][2], acc[o][3]));
      out[((long)img * 25 + oc0 + o) * 444 + (p0 + r) * 12 + j] =
          fmaxf(mx + bias[oc0 + o], 0.f);
    }
  }
}

// ---------------- fused stats + NCC + relu + red1 (one channel per block) ---------
__global__ __launch_bounds__(128) void k_ncc(
    const float* __restrict__ f, const float* __restrict__ wr1t,
    float* __restrict__ red1) {
  int b  = blockIdx.x;          // 0..63
  int g  = blockIdx.y;          // 0..3 -> rows i0..i0+ROWS-1
  int c  = blockIdx.z;          // 0..24 channel
  int i0 = g * 10;
  int ROWS = min(10, 37 - i0);
  int tid = threadIdx.x;
  int j = tid % 12, r = tid / 12;
  bool active = (r < ROWS);

  __shared__ float Xt[14][17];
  __shared__ __align__(16) float Yt[18][20];
  __shared__ float mX[10][12], iX[10][12];
  __shared__ float mY[14][12], iY[14][12];   // mY = muY*ivY, iY = ivY

  const float* Xf = f + (long)b * 25 * 444 + c * 444;
  const float* Yf = f + (long)(64 + b) * 25 * 444 + c * 444;

  for (int idx = tid; idx < 14 * 16; idx += 128) {
    int rr = idx >> 4, cl = idx & 15;
    int gi = i0 - 2 + rr, gj = cl - 2;
    Xt[rr][cl] = (gi >= 0 && gi < 37 && gj >= 0 && gj < 12)
                     ? Xf[gi * 12 + gj] : 0.f;
  }
  for (int idx = tid; idx < 18 * 16; idx += 128) {
    int rr = idx >> 4, cl = idx & 15;
    int gi = i0 - 4 + rr, gj = cl - 2;
    Yt[rr][cl] = (gi >= 0 && gi < 37 && gj >= 0 && gj < 12)
                     ? Yf[gi * 12 + gj] : 0.f;
  }
  for (int idx = tid; idx < 18 * 4; idx += 128) {
    int rr = idx >> 2;
    Yt[rr][16 + (idx & 3)] = 0.f;   // pad cols 16..19
  }
  __syncthreads();

  // ---- in-block patch stats from staged tiles ----
  for (int idx = tid; idx < 120; idx += 128) {
    int rr = idx / 12, gj = idx % 12;
    bool ok = (i0 + rr) < 37;
    float s = 0.f, sq = 0.f;
#pragma unroll
    for (int u = 0; u < 5; ++u)
#pragma unroll
      for (int v = 0; v < 5; ++v) {
        float xv = Xt[rr + u][gj + v];
        s += xv;
        sq = fmaf(xv, xv, sq);
      }
    float m = s * 0.04f;
    float var = sq * 0.04f - m * m;
    float sd = sqrtf(fmaxf(var, 0.f));
    float ivv = 1.f / (sd + 0.01f);
    mX[rr][gj] = ok ? m : 0.f;
    iX[rr][gj] = ok ? ivv : 0.f;
  }
  for (int idx = tid; idx < 168; idx += 128) {
    int rr = idx / 12, gj = idx % 12;
    int gi = i0 - 2 + rr;
    bool ok = (gi >= 0 && gi < 37);
    float s = 0.f, sq = 0.f;
#pragma unroll
    for (int u = 0; u < 5; ++u)
#pragma unroll
      for (int v = 0; v < 5; ++v) {
        float yv = Yt[rr + u][gj + v];
        s += yv;
        sq = fmaf(yv, yv, sq);
      }
    float m = s * 0.04f;
    float var = sq * 0.04f - m * m;
    float sd = sqrtf(fmaxf(var, 0.f));
    float ivv = 1.f / (sd + 0.01f);
    mY[rr][gj] = ok ? m * ivv : 0.f;
    iY[rr][gj] = ok ? ivv : 0.f;
  }
  __syncthreads();

  float acc[25];
#pragma unroll
  for (int o = 0; o < 25; ++o) acc[o] = 0.f;

  if (active) {
    float xp[5][5];
#pragma unroll
    for (int u = 0; u < 5; ++u)
#pragma unroll
      for (int v = 0; v < 5; ++v) xp[u][v] = Xt[r + u][j + v];
    float muXv = mX[r][j], ivXv = iX[r][j];
    float sX = ivXv * 0.04f;
    float tX = muXv * ivXv;
    const float* wb = wr1t + c * 1680;     // 60 rows * 28 padded
#pragma unroll 1
    for (int d = 0; d < 5; ++d) {
      float rd[12];
#pragma unroll
      for (int k = 0; k < 12; ++k) rd[k] = 0.f;
#pragma unroll
      for (int u = 0; u < 5; ++u) {
        float yrow[16];
        const float* yb = &Yt[r + d + u][0];
        *reinterpret_cast<float4*>(&yrow[0])  = *reinterpret_cast<const float4*>(yb);
        *reinterpret_cast<float4*>(&yrow[4])  = *reinterpret_cast<const float4*>(yb + 4);
        *reinterpret_cast<float4*>(&yrow[8])  = *reinterpret_cast<const float4*>(yb + 8);
        *reinterpret_cast<float4*>(&yrow[12]) = *reinterpret_cast<const float4*>(yb + 12);
#pragma unroll
        for (int k = 0; k < 12; ++k)
#pragma unroll
          for (int v = 0; v < 5; ++v)
            rd[k] = fmaf(xp[u][v], yrow[k + v], rd[k]);
      }
#pragma unroll
      for (int k = 0; k < 12; ++k) {
        float ivYv = iY[r + d][k];
        float miYv = mY[r + d][k];
        float rv = fmaxf(fmaf(-tX, miYv, rd[k] * sX * ivYv), 0.f);
        const float* wrow = wb + (d * 12 + k) * 28;
        float wv[25];
        *reinterpret_cast<float4*>(&wv[0])  = *reinterpret_cast<const float4*>(wrow);
        *reinterpret_cast<float4*>(&wv[4])  = *reinterpret_cast<const float4*>(wrow + 4);
        *reinterpret_cast<float4*>(&wv[8])  = *reinterpret_cast<const float4*>(wrow + 8);
        *reinterpret_cast<float4*>(&wv[12]) = *reinterpret_cast<const float4*>(wrow + 12);
        *reinterpret_cast<float4*>(&wv[16]) = *reinterpret_cast<const float4*>(wrow + 16);
        *reinterpret_cast<float4*>(&wv[20]) = *reinterpret_cast<const float4*>(wrow + 20);
        wv[24] = wrow[24];
#pragma unroll
        for (int o = 0; o < 25; ++o) acc[o] = fmaf(wv[o], rv, acc[o]);
      }
    }
  }

  if (active) {
    int i = i0 + r;
    float* p = red1 + (long)b * 25 * 444 + i * 12 + j;
#pragma unroll
    for (int o = 0; o < 25; ++o) atomicAdd(p + o * 444, acc[o]);
  }
}

// ---------------- red2 3x3 conv + pool (oc-group split; bias+relu on load) --------
__global__ __launch_bounds__(256) void k_red2(
    const float* __restrict__ red1, const float* __restrict__ br1,
    const float* __restrict__ w, const float* __restrict__ bias,
    float* __restrict__ r2p) {
  int b = blockIdx.x;
  int oc0 = blockIdx.y * 5;
  __shared__ float inb[25 * 444];
  __shared__ float wl[5 * 25 * 9];
  for (int idx = threadIdx.x; idx < 25 * 444; idx += 256)
    inb[idx] = fmaxf(red1[(long)b * 25 * 444 + idx] + br1[idx / 444], 0.f);
  for (int idx = threadIdx.x; idx < 5 * 25 * 9; idx += 256)
    wl[idx] = w[oc0 * 25 * 9 + idx];
  __syncthreads();
  for (int item = threadIdx.x; item < 5 * 85; item += 256) {
    int ol = item / 85, rem = item % 85;
    int pi = rem / 5, pj = rem % 5;
    int ci0 = 2 * pi, cj0 = 2 * pj;
    float a00 = 0, a01 = 0, a10 = 0, a11 = 0;
    for (int ic = 0; ic < 25; ++ic) {
      const float* xp = inb + ic * 444 + ci0 * 12 + cj0;
      float win[4][4];
#pragma unroll
      for (int u = 0; u < 4; ++u)
#pragma unroll
        for (int v = 0; v < 4; ++v) win[u][v] = xp[u * 12 + v];
      const float* wq = wl + (ol * 25 + ic) * 9;
#pragma unroll
      for (int u = 0; u < 3; ++u)
#pragma unroll
        for (int v = 0; v < 3; ++v) {
          float wv = wq[u * 3 + v];
          a00 += wv * win[u][v];
          a01 += wv * win[u][v + 1];
          a10 += wv * win[u + 1][v];
          a11 += wv * win[u + 1][v + 1];
        }
    }
    float mx = fmaxf(fmaxf(a00, a01), fmaxf(a10, a11));
    r2p[(long)b * 2125 + (oc0 + ol) * 85 + rem] = mx + bias[oc0 + ol];
  }
}

// ---------------- lin1 GEMM partials (reads wl1 directly, no pre-transpose) -------
__global__ __launch_bounds__(256) void k_lin1p(
    const float* __restrict__ r2p, const float* __restrict__ wl1,
    float* __restrict__ part) {
  int nb = blockIdx.x;           // o-tile: o0 = nb*64
  int kc = blockIdx.y;           // t-chunk: t0 = kc*125
  int o0 = nb * 64, t0 = kc * 125;
  int tid = threadIdx.x;
  __shared__ float Xs[64][126];
  __shared__ __align__(16) float Ws[125][68];
  for (int idx = tid; idx < 64 * 125; idx += 256) {
    int b = idx / 125, tt = idx % 125;
    Xs[b][tt] = r2p[(long)b * 2125 + t0 + tt];
  }
  for (int idx = tid; idx < 64 * 125; idx += 256) {
    int oo = idx / 125, tt = idx % 125;
    int o = o0 + oo;
    Ws[tt][oo] = (o < 500) ? wl1[(long)o * 2125 + t0 + tt] : 0.f;
  }
  __syncthreads();
  int b0 = (tid >> 4) << 2;
  int ol = (tid & 15) << 2;
  float acc[4][4];
#pragma unroll
  for (int i = 0; i < 4; ++i)
#pragma unroll
    for (int q = 0; q < 4; ++q) acc[i][q] = 0.f;
  for (int tt = 0; tt < 125; ++tt) {
    float xv[4];
#pragma unroll
    for (int i = 0; i < 4; ++i) xv[i] = Xs[b0 + i][tt];
    float4 wv = *reinterpret_cast<const float4*>(&Ws[tt][ol]);
#pragma unroll
    for (int i = 0; i < 4; ++i) {
      acc[i][0] += xv[i] * wv.x;
      acc[i][1] += xv[i] * wv.y;
      acc[i][2] += xv[i] * wv.z;
      acc[i][3] += xv[i] * wv.w;
    }
  }
#pragma unroll
  for (int i = 0; i < 4; ++i)
#pragma unroll
    for (int q = 0; q < 4; ++q)
      part[((long)kc * 64 + (b0 + i)) * 512 + o0 + ol + q] = acc[i][q];
}

// ---------------- lin1 reduce + bias, then lin2 fused ----------------
__global__ __launch_bounds__(512) void k_lin2(
    const float* __restrict__ part, const float* __restrict__ bl1,
    const float* __restrict__ wl2, const float* __restrict__ bl2,
    float* __restrict__ out) {
  int b = blockIdx.x;
  int o = threadIdx.x;
  float s = 0.f;
  if (o < 500) {
#pragma unroll
    for (int kc = 0; kc < 17; ++kc) s += part[((long)kc * 64 + b) * 512 + o];
    s += bl1[o];
  }
  __shared__ float red0[512], red1s[512];
  red0[o]  = (o < 500) ? s * wl2[o] : 0.f;
  red1s[o] = (o < 500) ? s * wl2[500 + o] : 0.f;
  __syncthreads();
  for (int st = 256; st >= 1; st >>= 1) {
    if (o < st) { red0[o] += red0[o + st]; red1s[o] += red1s[o + st]; }
    __syncthreads();
  }
  if (o == 0) {
    out[b * 2 + 0] = red0[0] + bl2[0];
    out[b * 2 + 1] = red1s[0] + bl2[1];
  }
}

// ---------------- launch ----------------
extern "C" void kernel_launch(void* const* d_in, const int* in_sizes, int n_in,
                              void* d_out, int out_size, void* d_ws, size_t ws_size,
                              hipStream_t stream) {
  const float* x1   = (const float*)d_in[0];
  const float* x2   = (const float*)d_in[1];
  const float* w1   = (const float*)d_in[2];
  const float* b1   = (const float*)d_in[3];
  const float* w2   = (const float*)d_in[4];
  const float* b2   = (const float*)d_in[5];
  const float* wr1  = (const float*)d_in[6];
  const float* br1  = (const float*)d_in[7];
  const float* wr2  = (const float*)d_in[8];
  const float* br2  = (const float*)d_in[9];
  const float* wl1  = (const float*)d_in[10];
  const float* bl1  = (const float*)d_in[11];
  const float* wl2  = (const float*)d_in[12];
  const float* bl2  = (const float*)d_in[13];
  float* out = (float*)d_out;
  float* ws  = (float*)d_ws;

  float* c1    = ws + OFF_C1;
  float* f     = ws + OFF_F;
  float* red1  = ws + OFF_RED1;
  float* r2p   = ws + OFF_R2P;
  float* wr1t  = ws + OFF_WR1T;
  float* linp  = ws + OFF_LINP;

  hipLaunchKernelGGL(k_conv1, dim3(128, 6, 4), dim3(256), 0, stream, x1, x2, w1, b1, c1);
  hipLaunchKernelGGL(k_conv2, dim3(128, 4, 5), dim3(128), 0, stream, c1, w2, b2, f);

  // wr1t lives in the (now dead) c1 region -> must launch after conv2
  hipLaunchKernelGGL(k_wrt, dim3(147), dim3(256), 0, stream, wr1, wr1t);

  // zero red1 accumulator (graph-capturable stream op), then fused stats+NCC+red1
  hipMemsetAsync(red1, 0, 710400 * sizeof(float), stream);
  hipLaunchKernelGGL(k_ncc, dim3(64, 4, 25), dim3(128), 0, stream, f, wr1t, red1);

  hipLaunchKernelGGL(k_red2, dim3(64, 5), dim3(256), 0, stream, red1, br1, wr2, br2, r2p);

  hipLaunchKernelGGL(k_lin1p, dim3(8, 17), dim3(256), 0, stream, r2p, wl1, linp);
  hipLaunchKernelGGL(k_lin2, dim3(64), dim3(512), 0, stream, linp, bl1, wl2, bl2, out);
}